// Round 1
// baseline (1156.961 us; speedup 1.0000x reference)
//
#include <hip/hip_runtime.h>

typedef unsigned short u16;
typedef unsigned int u32;
typedef __attribute__((ext_vector_type(8))) short short8;
typedef __attribute__((ext_vector_type(4))) float f32x4;

// Problem constants: B=16, N=256, T=4096, D=1024, H=8, DH=128
#define SCALE 0.08838834764831845f
#define OUT_ELEMS 33554432ull  // 16*256*8*1024

__device__ __forceinline__ u16 f2b(float f) {  // f32 -> bf16 RNE
  u32 u = __float_as_uint(f);
  u32 r = u + 0x7fffu + ((u >> 16) & 1u);
  return (u16)(r >> 16);
}

__device__ __forceinline__ void gload16(const void* g, void* l) {
  // async global->LDS, 16B per lane; LDS dest = wave-uniform base + lane*16
  __builtin_amdgcn_global_load_lds((const __attribute__((address_space(1))) void*)g,
                                   (__attribute__((address_space(3))) void*)l, 16, 0, 0);
}

// ---------------- LayerNorm rows of length 1024 -> bf16 (scale folded) -------
__global__ __launch_bounds__(256) void ln_rows(const float* __restrict__ in,
                                               const float* __restrict__ gamma,
                                               u16* __restrict__ out, float scale) {
  const int row = blockIdx.x;
  const int t = threadIdx.x;
  const float4 v = *(const float4*)(in + (size_t)row * 1024 + t * 4);
  float s = v.x + v.y + v.z + v.w;
  float q = v.x * v.x + v.y * v.y + v.z * v.z + v.w * v.w;
#pragma unroll
  for (int m = 32; m; m >>= 1) {
    s += __shfl_down(s, m);
    q += __shfl_down(q, m);
  }
  __shared__ float red[8];
  const int w = t >> 6;
  if ((t & 63) == 0) { red[w] = s; red[4 + w] = q; }
  __syncthreads();
  s = red[0] + red[1] + red[2] + red[3];
  q = red[4] + red[5] + red[6] + red[7];
  const float mu = s * (1.0f / 1024.0f);
  const float var = q * (1.0f / 1024.0f) - mu * mu;
  const float rs = rsqrtf(var + 1e-5f) * scale;
  const float4 g = *(const float4*)(gamma + t * 4);
  ushort4 o;
  o.x = f2b((v.x - mu) * rs * g.x);
  o.y = f2b((v.y - mu) * rs * g.y);
  o.z = f2b((v.z - mu) * rs * g.z);
  o.w = f2b((v.w - mu) * rs * g.w);
  *(ushort4*)(out + (size_t)row * 1024 + t * 4) = o;
}

// ---------------- W_kv[:, :128] -> Wt bf16 [128][1024] -----------------------
__global__ __launch_bounds__(256) void cvt_w(const float* __restrict__ w, u16* __restrict__ wt) {
  const int n = blockIdx.x;  // 0..127
  const int t = threadIdx.x;
  const int d = t * 4;
  ushort4 o;
  o.x = f2b(w[(size_t)(d + 0) * 256 + n]);
  o.y = f2b(w[(size_t)(d + 1) * 256 + n]);
  o.z = f2b(w[(size_t)(d + 2) * 256 + n]);
  o.w = f2b(w[(size_t)(d + 3) * 256 + n]);
  *(ushort4*)(wt + (size_t)n * 1024 + d) = o;
}

// ---------------- x_n [b][4096][1024] -> x_nT [b][1024][4096] (bf16) ---------
__global__ __launch_bounds__(256) void transpose_xn(const u16* __restrict__ xn,
                                                    u16* __restrict__ xnt) {
  const int jt = blockIdx.x, dt = blockIdx.y, b = blockIdx.z;
  __shared__ u16 tile[64][72];  // pad 8 keeps 16B alignment per row
  const int t = threadIdx.x;
  const size_t src = ((size_t)b * 4096 + jt * 64) * 1024 + dt * 64;
#pragma unroll
  for (int p = 0; p < 2; ++p) {
    const int idx = t + 256 * p;
    const int j = idx >> 3, c = idx & 7;
    *(short8*)(&tile[j][c * 8]) = *(const short8*)(xn + src + (size_t)j * 1024 + c * 8);
  }
  __syncthreads();
  const size_t dst = ((size_t)b * 1024 + dt * 64) * 4096 + jt * 64;
#pragma unroll
  for (int p = 0; p < 2; ++p) {
    const int idx = t + 256 * p;
    const int d = idx >> 3, jj = idx & 7;
    short8 o;
#pragma unroll
    for (int e = 0; e < 8; ++e) o[e] = (short)tile[jj * 8 + e][d];
    *(short8*)(xnt + dst + (size_t)d * 4096 + jj * 8) = o;
  }
}

// ---------------- k = x_n @ W[:, :128]  (M=65536, N=128, K=1024) -------------
__global__ __launch_bounds__(256) void kgemm(const u16* __restrict__ xn,
                                             const u16* __restrict__ wt,
                                             u16* __restrict__ ks) {
  __shared__ u16 As[128 * 32];
  __shared__ u16 Bs[128 * 32];
  const int t = threadIdx.x;
  const int lane = t & 63, w = t >> 6;
  const int wm = w >> 1, wn = w & 1;
  const int j0 = blockIdx.x * 128;
  const int g = lane >> 4, r16 = lane & 15;
  f32x4 acc[4][4] = {};
  for (int k0 = 0; k0 < 1024; k0 += 32) {
    __syncthreads();
#pragma unroll
    for (int i = 0; i < 2; ++i) {
      const int seg = i * 4 + w;
      const int off = seg * 1024 + lane * 16;  // linear LDS byte offset
      const int row = off >> 6;                // 64B per row (32 bf16)
      const int c = (off >> 4) & 3;            // 16B chunk in row
      const int sw = c ^ ((row >> 1) & 3);     // inverse-swizzled global source
      gload16(xn + ((size_t)(j0 + row)) * 1024 + k0 + sw * 8, (char*)As + seg * 1024);
      gload16(wt + ((size_t)row) * 1024 + k0 + sw * 8, (char*)Bs + seg * 1024);
    }
    __syncthreads();
    short8 a[4], bq[4];
#pragma unroll
    for (int mt = 0; mt < 4; ++mt) {
      const int row = wm * 64 + mt * 16 + r16;
      const int sw = g ^ ((row >> 1) & 3);
      a[mt] = *(const short8*)(As + row * 32 + sw * 8);
    }
#pragma unroll
    for (int nt = 0; nt < 4; ++nt) {
      const int row = wn * 64 + nt * 16 + r16;
      const int sw = g ^ ((row >> 1) & 3);
      bq[nt] = *(const short8*)(Bs + row * 32 + sw * 8);
    }
#pragma unroll
    for (int mt = 0; mt < 4; ++mt)
#pragma unroll
      for (int nt = 0; nt < 4; ++nt)
        acc[mt][nt] = __builtin_amdgcn_mfma_f32_16x16x32_bf16(a[mt], bq[nt], acc[mt][nt], 0, 0, 0);
  }
#pragma unroll
  for (int mt = 0; mt < 4; ++mt)
#pragma unroll
    for (int nt = 0; nt < 4; ++nt)
#pragma unroll
      for (int r = 0; r < 4; ++r) {
        const int j = j0 + wm * 64 + mt * 16 + g * 4 + r;
        const int n = wn * 64 + nt * 16 + r16;
        ks[(size_t)j * 128 + n] = f2b(acc[mt][nt][r]);
      }
}

// ---------------- sim + softmax -> attn (f32) --------------------------------
// block = (b, h, 16 q-rows); 16 waves, wave w covers j in [w*256, w*256+256)
__global__ __launch_bounds__(1024) void attn_kernel(const u16* __restrict__ qs,
                                                    const u16* __restrict__ ks,
                                                    float* __restrict__ attn) {
  const int blk = blockIdx.x;
  const int it = blk & 15, h = (blk >> 4) & 7, b = blk >> 7;
  const int i0 = it * 16;
  const int t = threadIdx.x;
  const int lane = t & 63, w = t >> 6;
  const int g = lane >> 4, r16 = lane & 15;
  __shared__ u16 Q[16 * 128];
  __shared__ float redm[16 * 16];
  __shared__ float reds[16 * 16];
  if (t < 256) {
    const int row = t >> 4, c = t & 15;
    const int sw = c ^ (row & 7);
    *(short8*)(Q + row * 128 + sw * 8) =
        *(const short8*)(qs + ((size_t)(b * 256 + i0 + row)) * 1024 + h * 128 + c * 8);
  }
  __syncthreads();
  short8 a[4];
#pragma unroll
  for (int kp = 0; kp < 4; ++kp) {
    const int c = kp * 4 + g;
    const int sw = c ^ (r16 & 7);
    a[kp] = *(const short8*)(Q + r16 * 128 + sw * 8);
  }
  const u16* kb = ks + (size_t)b * 4096 * 128;
  const int j0 = w * 256;
  f32x4 acc[16] = {};
#pragma unroll
  for (int kp = 0; kp < 4; ++kp) {
#pragma unroll
    for (int nt = 0; nt < 16; ++nt) {
      const short8 bv = *(const short8*)(kb + (size_t)(j0 + nt * 16 + r16) * 128 + kp * 32 + g * 8);
      acc[nt] = __builtin_amdgcn_mfma_f32_16x16x32_bf16(a[kp], bv, acc[nt], 0, 0, 0);
    }
  }
  // per-lane rows are i_local = g*4 + r; cols j = j0 + nt*16 + r16
  float mx[4];
#pragma unroll
  for (int r = 0; r < 4; ++r) {
    float m = acc[0][r];
#pragma unroll
    for (int nt = 1; nt < 16; ++nt) m = fmaxf(m, acc[nt][r]);
    mx[r] = m;
  }
#pragma unroll
  for (int msk = 1; msk < 16; msk <<= 1) {
#pragma unroll
    for (int r = 0; r < 4; ++r) mx[r] = fmaxf(mx[r], __shfl_xor(mx[r], msk));
  }
  if (r16 == 0) {
#pragma unroll
    for (int r = 0; r < 4; ++r) redm[w * 16 + g * 4 + r] = mx[r];
  }
  __syncthreads();
#pragma unroll
  for (int r = 0; r < 4; ++r) {
    float m = redm[g * 4 + r];
    for (int w2 = 1; w2 < 16; ++w2) m = fmaxf(m, redm[w2 * 16 + g * 4 + r]);
    mx[r] = m;
  }
  float sm[4] = {0.f, 0.f, 0.f, 0.f};
#pragma unroll
  for (int nt = 0; nt < 16; ++nt) {
#pragma unroll
    for (int r = 0; r < 4; ++r) {
      const float p = __expf(acc[nt][r] - mx[r]);
      acc[nt][r] = p;
      sm[r] += p;
    }
  }
#pragma unroll
  for (int msk = 1; msk < 16; msk <<= 1) {
#pragma unroll
    for (int r = 0; r < 4; ++r) sm[r] += __shfl_xor(sm[r], msk);
  }
  if (r16 == 0) {
#pragma unroll
    for (int r = 0; r < 4; ++r) reds[w * 16 + g * 4 + r] = sm[r];
  }
  __syncthreads();
  float inv[4];
#pragma unroll
  for (int r = 0; r < 4; ++r) {
    float s = reds[g * 4 + r];
    for (int w2 = 1; w2 < 16; ++w2) s += reds[w2 * 16 + g * 4 + r];
    inv[r] = 1.0f / s;
  }
  float* arow = attn + ((size_t)(b * 8 + h) * 256 + i0) * 4096 + j0;
#pragma unroll
  for (int nt = 0; nt < 16; ++nt) {
#pragma unroll
    for (int r = 0; r < 4; ++r)
      arow[(size_t)(g * 4 + r) * 4096 + nt * 16 + r16] = acc[nt][r] * inv[r];
  }
}

// ---------------- out = attn @ x_n  per (b,h): [256 x 4096] @ [4096 x 1024] --
__global__ __launch_bounds__(256) void ogemm(const float* __restrict__ attn,
                                             const u16* __restrict__ xnt,
                                             float* __restrict__ out) {
  // XCD-chunked swizzle (grid 2048 % 8 == 0): 8 f-tiles sharing an A-panel
  // become consecutive work on one XCD -> A panel L2-resident.
  const int orig = blockIdx.x;
  const int wid = (orig & 7) * 256 + (orig >> 3);
  const int ft = wid & 7;       // f tile (of 128)
  const int mtile = wid >> 3;   // 0..255
  const int bh = mtile >> 1, mh = mtile & 1;
  const int b = bh >> 3, h = bh & 7;
  __shared__ u16 As[128 * 32];
  __shared__ u16 Bs[128 * 32];
  const int t = threadIdx.x;
  const int lane = t & 63, w = t >> 6;
  const int wm = w >> 1, wn = w & 1;
  const int g = lane >> 4, r16 = lane & 15;
  const float* Ab = attn + ((size_t)bh * 256 + mh * 128) * 4096;
  const u16* Bb = xnt + ((size_t)b * 1024 + ft * 128) * 4096;
  const int arow = t >> 1, ahalf = t & 1;
  const float* ap = Ab + (size_t)arow * 4096 + ahalf * 16;
  const int asw = (arow >> 1) & 3;
  u16* aw0 = As + arow * 32 + (((ahalf * 2 + 0) ^ asw) * 8);
  u16* aw1 = As + arow * 32 + (((ahalf * 2 + 1) ^ asw) * 8);
  f32x4 acc[4][4] = {};
  float4 v0 = *(const float4*)(ap + 0);
  float4 v1 = *(const float4*)(ap + 4);
  float4 v2 = *(const float4*)(ap + 8);
  float4 v3 = *(const float4*)(ap + 12);
  for (int kt = 0; kt < 128; ++kt) {
    __syncthreads();
    short8 pa, pb;
    pa[0] = (short)f2b(v0.x); pa[1] = (short)f2b(v0.y);
    pa[2] = (short)f2b(v0.z); pa[3] = (short)f2b(v0.w);
    pa[4] = (short)f2b(v1.x); pa[5] = (short)f2b(v1.y);
    pa[6] = (short)f2b(v1.z); pa[7] = (short)f2b(v1.w);
    pb[0] = (short)f2b(v2.x); pb[1] = (short)f2b(v2.y);
    pb[2] = (short)f2b(v2.z); pb[3] = (short)f2b(v2.w);
    pb[4] = (short)f2b(v3.x); pb[5] = (short)f2b(v3.y);
    pb[6] = (short)f2b(v3.z); pb[7] = (short)f2b(v3.w);
    *(short8*)aw0 = pa;
    *(short8*)aw1 = pb;
#pragma unroll
    for (int i = 0; i < 2; ++i) {
      const int seg = i * 4 + w;
      const int off = seg * 1024 + lane * 16;
      const int row = off >> 6;
      const int c = (off >> 4) & 3;
      const int sw = c ^ ((row >> 1) & 3);
      gload16(Bb + (size_t)row * 4096 + kt * 32 + sw * 8, (char*)Bs + seg * 1024);
    }
    if (kt < 127) {  // prefetch next A slab into regs (hidden under barrier/mfma)
      const float* p = ap + (kt + 1) * 32;
      v0 = *(const float4*)(p + 0);
      v1 = *(const float4*)(p + 4);
      v2 = *(const float4*)(p + 8);
      v3 = *(const float4*)(p + 12);
    }
    __syncthreads();
    short8 a[4], bq[4];
#pragma unroll
    for (int mt = 0; mt < 4; ++mt) {
      const int row = wm * 64 + mt * 16 + r16;
      const int sw = g ^ ((row >> 1) & 3);
      a[mt] = *(const short8*)(As + row * 32 + sw * 8);
    }
#pragma unroll
    for (int nt = 0; nt < 4; ++nt) {
      const int row = wn * 64 + nt * 16 + r16;
      const int sw = g ^ ((row >> 1) & 3);
      bq[nt] = *(const short8*)(Bs + row * 32 + sw * 8);
    }
#pragma unroll
    for (int mt = 0; mt < 4; ++mt)
#pragma unroll
      for (int nt = 0; nt < 4; ++nt)
        acc[mt][nt] = __builtin_amdgcn_mfma_f32_16x16x32_bf16(a[mt], bq[nt], acc[mt][nt], 0, 0, 0);
  }
#pragma unroll
  for (int mt = 0; mt < 4; ++mt)
#pragma unroll
    for (int nt = 0; nt < 4; ++nt)
#pragma unroll
      for (int r = 0; r < 4; ++r) {
        const int i = mh * 128 + wm * 64 + mt * 16 + g * 4 + r;
        const int f = ft * 128 + wn * 64 + nt * 16 + r16;
        out[(size_t)b * 2097152 + (size_t)i * 8192 + (size_t)h * 1024 + f] = acc[mt][nt][r];
      }
}

extern "C" void kernel_launch(void* const* d_in, const int* in_sizes, int n_in,
                              void* d_out, int out_size, void* d_ws, size_t ws_size,
                              hipStream_t stream) {
  const float* img_q = (const float*)d_in[0];
  const float* x = (const float*)d_in[1];
  const float* gamma_q = (const float*)d_in[2];
  const float* gamma_x = (const float*)d_in[3];
  const float* wkv = (const float*)d_in[4];

  float* out_f = (float*)d_out;
  float* attn_f = out_f + OUT_ELEMS;

  // Stashes aliasing not-yet-written d_out regions (all dead before overwrite):
  u16* xn = (u16*)attn_f;        // x_n bf16 [65536][1024], 128MB of attn region
  u16* qsb = (u16*)out_f;        // q bf16 (scaled) [16][256][1024], 8MB
  u16* wtb = qsb + 4194304;      // Wt bf16 [128][1024]
  u16* ksb = wtb + 131072;       // k bf16 [16][4096][128], 16MB
  u16* xnt = (u16*)d_ws;         // x_nT bf16 [16][1024][4096], 128MB (needs ws)

  if (ws_size < (size_t)134217728) return;  // need 128 MiB scratch for x_nT

  ln_rows<<<65536, 256, 0, stream>>>(x, gamma_x, xn, 1.0f);
  ln_rows<<<4096, 256, 0, stream>>>(img_q, gamma_q, qsb, SCALE);
  cvt_w<<<128, 256, 0, stream>>>(wkv, wtb);
  transpose_xn<<<dim3(64, 16, 16), 256, 0, stream>>>(xn, xnt);
  kgemm<<<512, 256, 0, stream>>>(xn, wtb, ksb);
  attn_kernel<<<2048, 1024, 0, stream>>>(qsb, ksb, attn_f);
  ogemm<<<2048, 256, 0, stream>>>(attn_f, xnt, out_f);
}

// Round 2
// 1139.585 us; speedup vs baseline: 1.0152x; 1.0152x over previous
//
#include <hip/hip_runtime.h>

typedef unsigned short u16;
typedef unsigned int u32;
typedef __attribute__((ext_vector_type(8))) short short8;
typedef __attribute__((ext_vector_type(4))) float f32x4;

// Problem constants: B=16, N=256, T=4096, D=1024, H=8, DH=128
#define SCALE 0.08838834764831845f
#define OUT_ELEMS 33554432ull  // 16*256*8*1024

__device__ __forceinline__ u16 f2b(float f) {  // f32 -> bf16 RNE
  u32 u = __float_as_uint(f);
  u32 r = u + 0x7fffu + ((u >> 16) & 1u);
  return (u16)(r >> 16);
}

__device__ __forceinline__ void gload16(const void* g, void* l) {
  // async global->LDS, 16B per lane; LDS dest = wave-uniform base + lane*16
  __builtin_amdgcn_global_load_lds((const __attribute__((address_space(1))) void*)g,
                                   (__attribute__((address_space(3))) void*)l, 16, 0, 0);
}

// ---------------- LayerNorm rows of length 1024 -> bf16 (scale folded) -------
__global__ __launch_bounds__(256) void ln_rows(const float* __restrict__ in,
                                               const float* __restrict__ gamma,
                                               u16* __restrict__ out, float scale) {
  const int row = blockIdx.x;
  const int t = threadIdx.x;
  const float4 v = *(const float4*)(in + (size_t)row * 1024 + t * 4);
  float s = v.x + v.y + v.z + v.w;
  float q = v.x * v.x + v.y * v.y + v.z * v.z + v.w * v.w;
#pragma unroll
  for (int m = 32; m; m >>= 1) {
    s += __shfl_down(s, m);
    q += __shfl_down(q, m);
  }
  __shared__ float red[8];
  const int w = t >> 6;
  if ((t & 63) == 0) { red[w] = s; red[4 + w] = q; }
  __syncthreads();
  s = red[0] + red[1] + red[2] + red[3];
  q = red[4] + red[5] + red[6] + red[7];
  const float mu = s * (1.0f / 1024.0f);
  const float var = q * (1.0f / 1024.0f) - mu * mu;
  const float rs = rsqrtf(var + 1e-5f) * scale;
  const float4 g = *(const float4*)(gamma + t * 4);
  ushort4 o;
  o.x = f2b((v.x - mu) * rs * g.x);
  o.y = f2b((v.y - mu) * rs * g.y);
  o.z = f2b((v.z - mu) * rs * g.z);
  o.w = f2b((v.w - mu) * rs * g.w);
  *(ushort4*)(out + (size_t)row * 1024 + t * 4) = o;
}

// ---------------- W_kv[:, :128] -> Wt bf16 [128][1024] -----------------------
__global__ __launch_bounds__(256) void cvt_w(const float* __restrict__ w, u16* __restrict__ wt) {
  const int n = blockIdx.x;  // 0..127
  const int t = threadIdx.x;
  const int d = t * 4;
  ushort4 o;
  o.x = f2b(w[(size_t)(d + 0) * 256 + n]);
  o.y = f2b(w[(size_t)(d + 1) * 256 + n]);
  o.z = f2b(w[(size_t)(d + 2) * 256 + n]);
  o.w = f2b(w[(size_t)(d + 3) * 256 + n]);
  *(ushort4*)(wt + (size_t)n * 1024 + d) = o;
}

// ---------------- x_n [b][4096][1024] -> x_nT [b][1024][4096] (bf16) ---------
__global__ __launch_bounds__(256) void transpose_xn(const u16* __restrict__ xn,
                                                    u16* __restrict__ xnt) {
  const int jt = blockIdx.x, dt = blockIdx.y, b = blockIdx.z;
  __shared__ u16 tile[64][72];  // pad 8 keeps 16B alignment per row
  const int t = threadIdx.x;
  const size_t src = ((size_t)b * 4096 + jt * 64) * 1024 + dt * 64;
#pragma unroll
  for (int p = 0; p < 2; ++p) {
    const int idx = t + 256 * p;
    const int j = idx >> 3, c = idx & 7;
    *(short8*)(&tile[j][c * 8]) = *(const short8*)(xn + src + (size_t)j * 1024 + c * 8);
  }
  __syncthreads();
  const size_t dst = ((size_t)b * 1024 + dt * 64) * 4096 + jt * 64;
#pragma unroll
  for (int p = 0; p < 2; ++p) {
    const int idx = t + 256 * p;
    const int d = idx >> 3, jj = idx & 7;
    short8 o;
#pragma unroll
    for (int e = 0; e < 8; ++e) o[e] = (short)tile[jj * 8 + e][d];
    *(short8*)(xnt + dst + (size_t)d * 4096 + jj * 8) = o;
  }
}

// ---------------- k = x_n @ W[:, :128]  (M=65536, N=128, K=1024) -------------
__global__ __launch_bounds__(256) void kgemm(const u16* __restrict__ xn,
                                             const u16* __restrict__ wt,
                                             u16* __restrict__ ks) {
  __shared__ u16 As[128 * 32];
  __shared__ u16 Bs[128 * 32];
  const int t = threadIdx.x;
  const int lane = t & 63, w = t >> 6;
  const int wm = w >> 1, wn = w & 1;
  const int j0 = blockIdx.x * 128;
  const int g = lane >> 4, r16 = lane & 15;
  f32x4 acc[4][4] = {};
  for (int k0 = 0; k0 < 1024; k0 += 32) {
    __syncthreads();
#pragma unroll
    for (int i = 0; i < 2; ++i) {
      const int seg = i * 4 + w;
      const int off = seg * 1024 + lane * 16;  // linear LDS byte offset
      const int row = off >> 6;                // 64B per row (32 bf16)
      const int c = (off >> 4) & 3;            // 16B chunk in row
      const int sw = c ^ ((row >> 1) & 3);     // inverse-swizzled global source
      gload16(xn + ((size_t)(j0 + row)) * 1024 + k0 + sw * 8, (char*)As + seg * 1024);
      gload16(wt + ((size_t)row) * 1024 + k0 + sw * 8, (char*)Bs + seg * 1024);
    }
    __syncthreads();
    short8 a[4], bq[4];
#pragma unroll
    for (int mt = 0; mt < 4; ++mt) {
      const int row = wm * 64 + mt * 16 + r16;
      const int sw = g ^ ((row >> 1) & 3);
      a[mt] = *(const short8*)(As + row * 32 + sw * 8);
    }
#pragma unroll
    for (int nt = 0; nt < 4; ++nt) {
      const int row = wn * 64 + nt * 16 + r16;
      const int sw = g ^ ((row >> 1) & 3);
      bq[nt] = *(const short8*)(Bs + row * 32 + sw * 8);
    }
#pragma unroll
    for (int mt = 0; mt < 4; ++mt)
#pragma unroll
      for (int nt = 0; nt < 4; ++nt)
        acc[mt][nt] = __builtin_amdgcn_mfma_f32_16x16x32_bf16(a[mt], bq[nt], acc[mt][nt], 0, 0, 0);
  }
#pragma unroll
  for (int mt = 0; mt < 4; ++mt)
#pragma unroll
    for (int nt = 0; nt < 4; ++nt)
#pragma unroll
      for (int r = 0; r < 4; ++r) {
        const int j = j0 + wm * 64 + mt * 16 + g * 4 + r;
        const int n = wn * 64 + nt * 16 + r16;
        ks[(size_t)j * 128 + n] = f2b(acc[mt][nt][r]);
      }
}

// ---------------- sim + softmax -> attn (f32) [+ optional bf16 copy] ---------
// block = (b, h, 16 q-rows); 16 waves, wave w covers j in [w*256, w*256+256)
__global__ __launch_bounds__(1024) void attn_kernel(const u16* __restrict__ qs,
                                                    const u16* __restrict__ ks,
                                                    float* __restrict__ attn,
                                                    u16* __restrict__ attnb) {
  const int blk = blockIdx.x;
  const int it = blk & 15, h = (blk >> 4) & 7, b = blk >> 7;
  const int i0 = it * 16;
  const int t = threadIdx.x;
  const int lane = t & 63, w = t >> 6;
  const int g = lane >> 4, r16 = lane & 15;
  __shared__ u16 Q[16 * 128];
  __shared__ float redm[16 * 16];
  __shared__ float reds[16 * 16];
  if (t < 256) {
    const int row = t >> 4, c = t & 15;
    const int sw = c ^ (row & 7);
    *(short8*)(Q + row * 128 + sw * 8) =
        *(const short8*)(qs + ((size_t)(b * 256 + i0 + row)) * 1024 + h * 128 + c * 8);
  }
  __syncthreads();
  short8 a[4];
#pragma unroll
  for (int kp = 0; kp < 4; ++kp) {
    const int c = kp * 4 + g;
    const int sw = c ^ (r16 & 7);
    a[kp] = *(const short8*)(Q + r16 * 128 + sw * 8);
  }
  const u16* kb = ks + (size_t)b * 4096 * 128;
  const int j0 = w * 256;
  f32x4 acc[16] = {};
#pragma unroll
  for (int kp = 0; kp < 4; ++kp) {
#pragma unroll
    for (int nt = 0; nt < 16; ++nt) {
      const short8 bv = *(const short8*)(kb + (size_t)(j0 + nt * 16 + r16) * 128 + kp * 32 + g * 8);
      acc[nt] = __builtin_amdgcn_mfma_f32_16x16x32_bf16(a[kp], bv, acc[nt], 0, 0, 0);
    }
  }
  // per-lane rows are i_local = g*4 + r; cols j = j0 + nt*16 + r16
  float mx[4];
#pragma unroll
  for (int r = 0; r < 4; ++r) {
    float m = acc[0][r];
#pragma unroll
    for (int nt = 1; nt < 16; ++nt) m = fmaxf(m, acc[nt][r]);
    mx[r] = m;
  }
#pragma unroll
  for (int msk = 1; msk < 16; msk <<= 1) {
#pragma unroll
    for (int r = 0; r < 4; ++r) mx[r] = fmaxf(mx[r], __shfl_xor(mx[r], msk));
  }
  if (r16 == 0) {
#pragma unroll
    for (int r = 0; r < 4; ++r) redm[w * 16 + g * 4 + r] = mx[r];
  }
  __syncthreads();
#pragma unroll
  for (int r = 0; r < 4; ++r) {
    float m = redm[g * 4 + r];
    for (int w2 = 1; w2 < 16; ++w2) m = fmaxf(m, redm[w2 * 16 + g * 4 + r]);
    mx[r] = m;
  }
  float sm[4] = {0.f, 0.f, 0.f, 0.f};
#pragma unroll
  for (int nt = 0; nt < 16; ++nt) {
#pragma unroll
    for (int r = 0; r < 4; ++r) {
      const float p = __expf(acc[nt][r] - mx[r]);
      acc[nt][r] = p;
      sm[r] += p;
    }
  }
#pragma unroll
  for (int msk = 1; msk < 16; msk <<= 1) {
#pragma unroll
    for (int r = 0; r < 4; ++r) sm[r] += __shfl_xor(sm[r], msk);
  }
  if (r16 == 0) {
#pragma unroll
    for (int r = 0; r < 4; ++r) reds[w * 16 + g * 4 + r] = sm[r];
  }
  __syncthreads();
  float inv[4];
#pragma unroll
  for (int r = 0; r < 4; ++r) {
    float s = reds[g * 4 + r];
    for (int w2 = 1; w2 < 16; ++w2) s += reds[w2 * 16 + g * 4 + r];
    inv[r] = 1.0f / s;
  }
  float* arow = attn + ((size_t)(b * 8 + h) * 256 + i0) * 4096 + j0;
  if (attnb) {
    u16* brow = attnb + ((size_t)(b * 8 + h) * 256 + i0) * 4096 + j0;
#pragma unroll
    for (int nt = 0; nt < 16; ++nt) {
#pragma unroll
      for (int r = 0; r < 4; ++r) {
        const float v = acc[nt][r] * inv[r];
        arow[(size_t)(g * 4 + r) * 4096 + nt * 16 + r16] = v;
        brow[(size_t)(g * 4 + r) * 4096 + nt * 16 + r16] = f2b(v);
      }
    }
  } else {
#pragma unroll
    for (int nt = 0; nt < 16; ++nt) {
#pragma unroll
      for (int r = 0; r < 4; ++r)
        arow[(size_t)(g * 4 + r) * 4096 + nt * 16 + r16] = acc[nt][r] * inv[r];
    }
  }
}

// ---------------- out = attnb @ x_nT  (pure bf16, m97 structure, BK=64) ------
__global__ __launch_bounds__(256) void ogemm_bf16(const u16* __restrict__ attnb,
                                                  const u16* __restrict__ xnt,
                                                  float* __restrict__ out) {
  // XCD-chunked swizzle (grid 2048 % 8 == 0): 8 f-tiles sharing an A-panel
  // land consecutively on one XCD -> A panel L2-resident.
  const int orig = blockIdx.x;
  const int wid = (orig & 7) * 256 + (orig >> 3);
  const int ft = wid & 7;       // f tile (of 128)
  const int mtile = wid >> 3;   // 0..255
  const int bh = mtile >> 1, mh = mtile & 1;
  const int b = bh >> 3, h = bh & 7;
  __shared__ u16 As[128 * 64];  // 16KB, swizzled: chunk c of row r at c^(r&7)
  __shared__ u16 Bs[128 * 64];
  const int t = threadIdx.x;
  const int lane = t & 63, w = t >> 6;
  const int wm = w >> 1, wn = w & 1;
  const int g = lane >> 4, r16 = lane & 15;
  const u16* Ab = attnb + ((size_t)bh * 256 + mh * 128) * 4096;
  const u16* Bb = xnt + ((size_t)b * 1024 + ft * 128) * 4096;
  f32x4 acc[4][4] = {};
  for (int k0 = 0; k0 < 4096; k0 += 64) {
    __syncthreads();
#pragma unroll
    for (int i = 0; i < 4; ++i) {
      const int seg = i * 4 + w;
      const int off = seg * 1024 + lane * 16;  // linear LDS byte offset
      const int row = off >> 7;                // 128B per row (64 bf16)
      const int c = (off >> 4) & 7;            // 16B chunk in row
      const int sw = c ^ (row & 7);            // inverse-swizzled global source
      gload16(Ab + (size_t)row * 4096 + k0 + sw * 8, (char*)As + seg * 1024);
      gload16(Bb + (size_t)row * 4096 + k0 + sw * 8, (char*)Bs + seg * 1024);
    }
    __syncthreads();
#pragma unroll
    for (int ks = 0; ks < 2; ++ks) {
      short8 a[4], bq[4];
#pragma unroll
      for (int mt = 0; mt < 4; ++mt) {
        const int row = wm * 64 + mt * 16 + r16;
        const int c = ks * 4 + g;
        a[mt] = *(const short8*)(As + row * 64 + ((c ^ (row & 7)) * 8));
      }
#pragma unroll
      for (int nt = 0; nt < 4; ++nt) {
        const int row = wn * 64 + nt * 16 + r16;
        const int c = ks * 4 + g;
        bq[nt] = *(const short8*)(Bs + row * 64 + ((c ^ (row & 7)) * 8));
      }
#pragma unroll
      for (int mt = 0; mt < 4; ++mt)
#pragma unroll
        for (int nt = 0; nt < 4; ++nt)
          acc[mt][nt] = __builtin_amdgcn_mfma_f32_16x16x32_bf16(a[mt], bq[nt], acc[mt][nt], 0, 0, 0);
    }
  }
#pragma unroll
  for (int mt = 0; mt < 4; ++mt)
#pragma unroll
    for (int nt = 0; nt < 4; ++nt)
#pragma unroll
      for (int r = 0; r < 4; ++r) {
        const int i = mh * 128 + wm * 64 + mt * 16 + g * 4 + r;
        const int f = ft * 128 + wn * 64 + nt * 16 + r16;
        out[(size_t)b * 2097152 + (size_t)i * 8192 + (size_t)h * 1024 + f] = acc[mt][nt][r];
      }
}

// ---------------- fallback: out = attn(f32) @ x_nT ---------------------------
__global__ __launch_bounds__(256) void ogemm(const float* __restrict__ attn,
                                             const u16* __restrict__ xnt,
                                             float* __restrict__ out) {
  const int orig = blockIdx.x;
  const int wid = (orig & 7) * 256 + (orig >> 3);
  const int ft = wid & 7;
  const int mtile = wid >> 3;
  const int bh = mtile >> 1, mh = mtile & 1;
  const int b = bh >> 3, h = bh & 7;
  __shared__ u16 As[128 * 32];
  __shared__ u16 Bs[128 * 32];
  const int t = threadIdx.x;
  const int lane = t & 63, w = t >> 6;
  const int wm = w >> 1, wn = w & 1;
  const int g = lane >> 4, r16 = lane & 15;
  const float* Ab = attn + ((size_t)bh * 256 + mh * 128) * 4096;
  const u16* Bb = xnt + ((size_t)b * 1024 + ft * 128) * 4096;
  const int arow = t >> 1, ahalf = t & 1;
  const float* ap = Ab + (size_t)arow * 4096 + ahalf * 16;
  const int asw = (arow >> 1) & 3;
  u16* aw0 = As + arow * 32 + (((ahalf * 2 + 0) ^ asw) * 8);
  u16* aw1 = As + arow * 32 + (((ahalf * 2 + 1) ^ asw) * 8);
  f32x4 acc[4][4] = {};
  float4 v0 = *(const float4*)(ap + 0);
  float4 v1 = *(const float4*)(ap + 4);
  float4 v2 = *(const float4*)(ap + 8);
  float4 v3 = *(const float4*)(ap + 12);
  for (int kt = 0; kt < 128; ++kt) {
    __syncthreads();
    short8 pa, pb;
    pa[0] = (short)f2b(v0.x); pa[1] = (short)f2b(v0.y);
    pa[2] = (short)f2b(v0.z); pa[3] = (short)f2b(v0.w);
    pa[4] = (short)f2b(v1.x); pa[5] = (short)f2b(v1.y);
    pa[6] = (short)f2b(v1.z); pa[7] = (short)f2b(v1.w);
    pb[0] = (short)f2b(v2.x); pb[1] = (short)f2b(v2.y);
    pb[2] = (short)f2b(v2.z); pb[3] = (short)f2b(v2.w);
    pb[4] = (short)f2b(v3.x); pb[5] = (short)f2b(v3.y);
    pb[6] = (short)f2b(v3.z); pb[7] = (short)f2b(v3.w);
    *(short8*)aw0 = pa;
    *(short8*)aw1 = pb;
#pragma unroll
    for (int i = 0; i < 2; ++i) {
      const int seg = i * 4 + w;
      const int off = seg * 1024 + lane * 16;
      const int row = off >> 6;
      const int c = (off >> 4) & 3;
      const int sw = c ^ ((row >> 1) & 3);
      gload16(Bb + (size_t)row * 4096 + kt * 32 + sw * 8, (char*)Bs + seg * 1024);
    }
    if (kt < 127) {
      const float* p = ap + (kt + 1) * 32;
      v0 = *(const float4*)(p + 0);
      v1 = *(const float4*)(p + 4);
      v2 = *(const float4*)(p + 8);
      v3 = *(const float4*)(p + 12);
    }
    __syncthreads();
    short8 a[4], bq[4];
#pragma unroll
    for (int mt = 0; mt < 4; ++mt) {
      const int row = wm * 64 + mt * 16 + r16;
      const int sw = g ^ ((row >> 1) & 3);
      a[mt] = *(const short8*)(As + row * 32 + sw * 8);
    }
#pragma unroll
    for (int nt = 0; nt < 4; ++nt) {
      const int row = wn * 64 + nt * 16 + r16;
      const int sw = g ^ ((row >> 1) & 3);
      bq[nt] = *(const short8*)(Bs + row * 32 + sw * 8);
    }
#pragma unroll
    for (int mt = 0; mt < 4; ++mt)
#pragma unroll
      for (int nt = 0; nt < 4; ++nt)
        acc[mt][nt] = __builtin_amdgcn_mfma_f32_16x16x32_bf16(a[mt], bq[nt], acc[mt][nt], 0, 0, 0);
  }
#pragma unroll
  for (int mt = 0; mt < 4; ++mt)
#pragma unroll
    for (int nt = 0; nt < 4; ++nt)
#pragma unroll
      for (int r = 0; r < 4; ++r) {
        const int i = mh * 128 + wm * 64 + mt * 16 + g * 4 + r;
        const int f = ft * 128 + wn * 64 + nt * 16 + r16;
        out[(size_t)b * 2097152 + (size_t)i * 8192 + (size_t)h * 1024 + f] = acc[mt][nt][r];
      }
}

extern "C" void kernel_launch(void* const* d_in, const int* in_sizes, int n_in,
                              void* d_out, int out_size, void* d_ws, size_t ws_size,
                              hipStream_t stream) {
  const float* img_q = (const float*)d_in[0];
  const float* x = (const float*)d_in[1];
  const float* gamma_q = (const float*)d_in[2];
  const float* gamma_x = (const float*)d_in[3];
  const float* wkv = (const float*)d_in[4];

  float* out_f = (float*)d_out;
  float* attn_f = out_f + OUT_ELEMS;

  // Stashes aliasing not-yet-written d_out regions (all dead before overwrite):
  u16* xn = (u16*)attn_f;        // x_n bf16 [65536][1024], 128MB of attn region
  u16* qsb = (u16*)out_f;        // q bf16 (scaled) [16][256][1024], 8MB
  u16* wtb = qsb + 4194304;      // Wt bf16 [128][1024]
  u16* ksb = wtb + 131072;       // k bf16 [16][4096][128], 16MB
  u16* xnt = (u16*)d_ws;         // x_nT bf16 [16][1024][4096], 128MiB

  if (ws_size < (size_t)134217728) return;  // need at least x_nT scratch

  // Fast path: bf16 copy of attn lives in ws after x_nT (256MiB more).
  const bool fast = ws_size >= (size_t)402653184;
  u16* attnb = fast ? (xnt + 67108864) : (u16*)nullptr;

  ln_rows<<<65536, 256, 0, stream>>>(x, gamma_x, xn, 1.0f);
  ln_rows<<<4096, 256, 0, stream>>>(img_q, gamma_q, qsb, SCALE);
  cvt_w<<<128, 256, 0, stream>>>(wkv, wtb);
  transpose_xn<<<dim3(64, 16, 16), 256, 0, stream>>>(xn, xnt);
  kgemm<<<512, 256, 0, stream>>>(xn, wtb, ksb);
  attn_kernel<<<2048, 1024, 0, stream>>>(qsb, ksb, attn_f, attnb);
  if (fast)
    ogemm_bf16<<<2048, 256, 0, stream>>>(attnb, xnt, out_f);
  else
    ogemm<<<2048, 256, 0, stream>>>(attn_f, xnt, out_f);
}

// Round 3
// 1021.976 us; speedup vs baseline: 1.1321x; 1.1151x over previous
//
#include <hip/hip_runtime.h>

typedef unsigned short u16;
typedef unsigned int u32;
typedef __attribute__((ext_vector_type(8))) short short8;
typedef __attribute__((ext_vector_type(4))) float f32x4;

// Problem constants: B=16, N=256, T=4096, D=1024, H=8, DH=128
#define SCALE 0.08838834764831845f
#define OUT_ELEMS 33554432ull  // 16*256*8*1024

__device__ __forceinline__ u16 f2b(float f) {  // f32 -> bf16 RNE
  u32 u = __float_as_uint(f);
  u32 r = u + 0x7fffu + ((u >> 16) & 1u);
  return (u16)(r >> 16);
}

__device__ __forceinline__ void gload16(const void* g, void* l) {
  // async global->LDS, 16B per lane; LDS dest = wave-uniform base + lane*16
  __builtin_amdgcn_global_load_lds((const __attribute__((address_space(1))) void*)g,
                                   (__attribute__((address_space(3))) void*)l, 16, 0, 0);
}

// ---------------- LayerNorm rows of length 1024 -> bf16 (scale folded) -------
__global__ __launch_bounds__(256) void ln_rows(const float* __restrict__ in,
                                               const float* __restrict__ gamma,
                                               u16* __restrict__ out, float scale) {
  const int row = blockIdx.x;
  const int t = threadIdx.x;
  const float4 v = *(const float4*)(in + (size_t)row * 1024 + t * 4);
  float s = v.x + v.y + v.z + v.w;
  float q = v.x * v.x + v.y * v.y + v.z * v.z + v.w * v.w;
#pragma unroll
  for (int m = 32; m; m >>= 1) {
    s += __shfl_down(s, m);
    q += __shfl_down(q, m);
  }
  __shared__ float red[8];
  const int w = t >> 6;
  if ((t & 63) == 0) { red[w] = s; red[4 + w] = q; }
  __syncthreads();
  s = red[0] + red[1] + red[2] + red[3];
  q = red[4] + red[5] + red[6] + red[7];
  const float mu = s * (1.0f / 1024.0f);
  const float var = q * (1.0f / 1024.0f) - mu * mu;
  const float rs = rsqrtf(var + 1e-5f) * scale;
  const float4 g = *(const float4*)(gamma + t * 4);
  ushort4 o;
  o.x = f2b((v.x - mu) * rs * g.x);
  o.y = f2b((v.y - mu) * rs * g.y);
  o.z = f2b((v.z - mu) * rs * g.z);
  o.w = f2b((v.w - mu) * rs * g.w);
  *(ushort4*)(out + (size_t)row * 1024 + t * 4) = o;
}

// ---------------- W_kv[:, :128] -> Wt bf16 [128][1024] -----------------------
__global__ __launch_bounds__(256) void cvt_w(const float* __restrict__ w, u16* __restrict__ wt) {
  const int n = blockIdx.x;  // 0..127
  const int t = threadIdx.x;
  const int d = t * 4;
  ushort4 o;
  o.x = f2b(w[(size_t)(d + 0) * 256 + n]);
  o.y = f2b(w[(size_t)(d + 1) * 256 + n]);
  o.z = f2b(w[(size_t)(d + 2) * 256 + n]);
  o.w = f2b(w[(size_t)(d + 3) * 256 + n]);
  *(ushort4*)(wt + (size_t)n * 1024 + d) = o;
}

// ---------------- x_n [b][4096][1024] -> x_nT [b][1024][4096] (bf16) ---------
__global__ __launch_bounds__(256) void transpose_xn(const u16* __restrict__ xn,
                                                    u16* __restrict__ xnt) {
  const int jt = blockIdx.x, dt = blockIdx.y, b = blockIdx.z;
  __shared__ u16 tile[64][72];  // pad 8 keeps 16B alignment per row
  const int t = threadIdx.x;
  const size_t src = ((size_t)b * 4096 + jt * 64) * 1024 + dt * 64;
#pragma unroll
  for (int p = 0; p < 2; ++p) {
    const int idx = t + 256 * p;
    const int j = idx >> 3, c = idx & 7;
    *(short8*)(&tile[j][c * 8]) = *(const short8*)(xn + src + (size_t)j * 1024 + c * 8);
  }
  __syncthreads();
  const size_t dst = ((size_t)b * 1024 + dt * 64) * 4096 + jt * 64;
#pragma unroll
  for (int p = 0; p < 2; ++p) {
    const int idx = t + 256 * p;
    const int d = idx >> 3, jj = idx & 7;
    short8 o;
#pragma unroll
    for (int e = 0; e < 8; ++e) o[e] = (short)tile[jj * 8 + e][d];
    *(short8*)(xnt + dst + (size_t)d * 4096 + jj * 8) = o;
  }
}

// ---------------- k = x_n @ W[:, :128]  (M=65536, N=128, K=1024) -------------
__global__ __launch_bounds__(256) void kgemm(const u16* __restrict__ xn,
                                             const u16* __restrict__ wt,
                                             u16* __restrict__ ks) {
  __shared__ u16 As[128 * 32];
  __shared__ u16 Bs[128 * 32];
  const int t = threadIdx.x;
  const int lane = t & 63, w = t >> 6;
  const int wm = w >> 1, wn = w & 1;
  const int j0 = blockIdx.x * 128;
  const int g = lane >> 4, r16 = lane & 15;
  f32x4 acc[4][4] = {};
  for (int k0 = 0; k0 < 1024; k0 += 32) {
    __syncthreads();
#pragma unroll
    for (int i = 0; i < 2; ++i) {
      const int seg = i * 4 + w;
      const int off = seg * 1024 + lane * 16;  // linear LDS byte offset
      const int row = off >> 6;                // 64B per row (32 bf16)
      const int c = (off >> 4) & 3;            // 16B chunk in row
      const int sw = c ^ ((row >> 1) & 3);     // inverse-swizzled global source
      gload16(xn + ((size_t)(j0 + row)) * 1024 + k0 + sw * 8, (char*)As + seg * 1024);
      gload16(wt + ((size_t)row) * 1024 + k0 + sw * 8, (char*)Bs + seg * 1024);
    }
    __syncthreads();
    short8 a[4], bq[4];
#pragma unroll
    for (int mt = 0; mt < 4; ++mt) {
      const int row = wm * 64 + mt * 16 + r16;
      const int sw = g ^ ((row >> 1) & 3);
      a[mt] = *(const short8*)(As + row * 32 + sw * 8);
    }
#pragma unroll
    for (int nt = 0; nt < 4; ++nt) {
      const int row = wn * 64 + nt * 16 + r16;
      const int sw = g ^ ((row >> 1) & 3);
      bq[nt] = *(const short8*)(Bs + row * 32 + sw * 8);
    }
#pragma unroll
    for (int mt = 0; mt < 4; ++mt)
#pragma unroll
      for (int nt = 0; nt < 4; ++nt)
        acc[mt][nt] = __builtin_amdgcn_mfma_f32_16x16x32_bf16(a[mt], bq[nt], acc[mt][nt], 0, 0, 0);
  }
#pragma unroll
  for (int mt = 0; mt < 4; ++mt)
#pragma unroll
    for (int nt = 0; nt < 4; ++nt)
#pragma unroll
      for (int r = 0; r < 4; ++r) {
        const int j = j0 + wm * 64 + mt * 16 + g * 4 + r;
        const int n = wn * 64 + nt * 16 + r16;
        ks[(size_t)j * 128 + n] = f2b(acc[mt][nt][r]);
      }
}

// ---------------- sim + softmax -> attn (f32) [+ bf16 copy] ------------------
// block = (b, h, 16 q-rows); 16 waves, wave w covers j in [w*256, w*256+256).
// SWAPPED QK^T: acc = mfma(K_frag, Q_frag) -> lane holds col i = r16 (q-row),
// rows j = g*4 + r (consecutive!). Enables full-line dwordx4 attn stores and
// shfl-only row reduction.
__global__ __launch_bounds__(1024) void attn_kernel(const u16* __restrict__ qs,
                                                    const u16* __restrict__ ks,
                                                    float* __restrict__ attn,
                                                    u16* __restrict__ attnb) {
  const int blk = blockIdx.x;
  const int it = blk & 15, h = (blk >> 4) & 7, b = blk >> 7;
  const int i0 = it * 16;
  const int t = threadIdx.x;
  const int lane = t & 63, w = t >> 6;
  const int g = lane >> 4, r16 = lane & 15;
  __shared__ u16 Q[16 * 128];
  __shared__ u16 rep[16 * 1024];  // per-wave 1024 u16 slice (16 rows x 64 j), reused x4
  __shared__ float redm[256];
  __shared__ float reds[256];
  if (t < 256) {
    const int row = t >> 4, c = t & 15;
    const int sw = c ^ (row & 7);
    *(short8*)(Q + row * 128 + sw * 8) =
        *(const short8*)(qs + ((size_t)(b * 256 + i0 + row)) * 1024 + h * 128 + c * 8);
  }
  __syncthreads();
  short8 a[4];
#pragma unroll
  for (int kp = 0; kp < 4; ++kp) {
    const int c = kp * 4 + g;
    const int sw = c ^ (r16 & 7);
    a[kp] = *(const short8*)(Q + r16 * 128 + sw * 8);
  }
  const u16* kb = ks + (size_t)b * 4096 * 128;
  const int j0 = w * 256;
  f32x4 acc[16] = {};
#pragma unroll
  for (int kp = 0; kp < 4; ++kp) {
#pragma unroll
    for (int nt = 0; nt < 16; ++nt) {
      const short8 bv = *(const short8*)(kb + (size_t)(j0 + nt * 16 + r16) * 128 + kp * 32 + g * 8);
      // swapped: K rows are the M dim (j), Q rows are the N dim (i)
      acc[nt] = __builtin_amdgcn_mfma_f32_16x16x32_bf16(bv, a[kp], acc[nt], 0, 0, 0);
    }
  }
  // lane holds 64 values: j = j0 + nt*16 + g*4 + r, all for q-row i = r16
  float mx = acc[0][0];
#pragma unroll
  for (int nt = 0; nt < 16; ++nt)
#pragma unroll
    for (int r = 0; r < 4; ++r) mx = fmaxf(mx, acc[nt][r]);
  mx = fmaxf(mx, __shfl_xor(mx, 16));
  mx = fmaxf(mx, __shfl_xor(mx, 32));  // now max over this wave's 256 j, per row r16
  if (lane < 16) redm[w * 16 + lane] = mx;
  __syncthreads();
  float m = redm[r16];
#pragma unroll
  for (int w2 = 1; w2 < 16; ++w2) m = fmaxf(m, redm[w2 * 16 + r16]);
  float sm = 0.f;
#pragma unroll
  for (int nt = 0; nt < 16; ++nt)
#pragma unroll
    for (int r = 0; r < 4; ++r) {
      const float p = __expf(acc[nt][r] - m);
      acc[nt][r] = p;
      sm += p;
    }
  sm += __shfl_xor(sm, 16);
  sm += __shfl_xor(sm, 32);
  if (lane < 16) reds[w * 16 + lane] = sm;
  __syncthreads();
  float s = reds[r16];
#pragma unroll
  for (int w2 = 1; w2 < 16; ++w2) s += reds[w2 * 16 + r16];
  const float inv = 1.0f / s;
#pragma unroll
  for (int nt = 0; nt < 16; ++nt) acc[nt] *= inv;

  // f32 attn: 16 dwordx4 stores, each instr = 16 rows x 64B full aligned lines
  float* arow = attn + ((size_t)((b * 8 + h) * 256 + i0 + r16)) * 4096 + j0;
#pragma unroll
  for (int nt = 0; nt < 16; ++nt)
    *(f32x4*)(arow + nt * 16 + g * 4) = acc[nt];

  // bf16 attnb via per-wave LDS repack -> contiguous full-line stores
  if (attnb) {
    u16* rslice = rep + w * 1024;
    u16* brow = attnb + ((size_t)((b * 8 + h) * 256 + i0)) * 4096 + j0;
    const int r7s = (r16 & 7) << 1;
    for (int q4 = 0; q4 < 4; ++q4) {
#pragma unroll
      for (int ntq = 0; ntq < 4; ++ntq) {
        const f32x4 v = acc[q4 * 4 + ntq];
        const u32 lo = (u32)f2b(v[0]) | ((u32)f2b(v[1]) << 16);
        const u32 hi = (u32)f2b(v[2]) | ((u32)f2b(v[3]) << 16);
        const int c8 = (ntq * 4 + g) ^ r7s;  // 8B-chunk XOR swizzle (keeps 16B pairing)
        *(uint2*)(rslice + r16 * 64 + c8 * 4) = make_uint2(lo, hi);
      }
      asm volatile("s_waitcnt lgkmcnt(0)" ::: "memory");
      __builtin_amdgcn_sched_barrier(0);
#pragma unroll
      for (int ih = 0; ih < 2; ++ih) {
        const int row = ih * 8 + (lane >> 3);
        const int c16 = lane & 7;
        const int c8 = (c16 * 2) ^ ((row & 7) << 1);
        const uint4 d = *(const uint4*)(rslice + row * 64 + c8 * 4);
        *(uint4*)(brow + (size_t)row * 4096 + q4 * 64 + c16 * 8) = d;
      }
      asm volatile("s_waitcnt lgkmcnt(0)" ::: "memory");
      __builtin_amdgcn_sched_barrier(0);
    }
  }
}

// ---------------- out = attnb @ x_nT  (pure bf16, m97 structure, BK=64) ------
__global__ __launch_bounds__(256) void ogemm_bf16(const u16* __restrict__ attnb,
                                                  const u16* __restrict__ xnt,
                                                  float* __restrict__ out) {
  // XCD-chunked swizzle (grid 2048 % 8 == 0): 8 f-tiles sharing an A-panel
  // land consecutively on one XCD -> A panel L2-resident.
  const int orig = blockIdx.x;
  const int wid = (orig & 7) * 256 + (orig >> 3);
  const int ft = wid & 7;       // f tile (of 128)
  const int mtile = wid >> 3;   // 0..255
  const int bh = mtile >> 1, mh = mtile & 1;
  const int b = bh >> 3, h = bh & 7;
  __shared__ u16 As[128 * 64];  // 16KB, swizzled: chunk c of row r at c^(r&7)
  __shared__ u16 Bs[128 * 64];
  const int t = threadIdx.x;
  const int lane = t & 63, w = t >> 6;
  const int wm = w >> 1, wn = w & 1;
  const int g = lane >> 4, r16 = lane & 15;
  const u16* Ab = attnb + ((size_t)bh * 256 + mh * 128) * 4096;
  const u16* Bb = xnt + ((size_t)b * 1024 + ft * 128) * 4096;
  f32x4 acc[4][4] = {};
  for (int k0 = 0; k0 < 4096; k0 += 64) {
    __syncthreads();
#pragma unroll
    for (int i = 0; i < 4; ++i) {
      const int seg = i * 4 + w;
      const int off = seg * 1024 + lane * 16;  // linear LDS byte offset
      const int row = off >> 7;                // 128B per row (64 bf16)
      const int c = (off >> 4) & 7;            // 16B chunk in row
      const int sw = c ^ (row & 7);            // inverse-swizzled global source
      gload16(Ab + (size_t)row * 4096 + k0 + sw * 8, (char*)As + seg * 1024);
      gload16(Bb + (size_t)row * 4096 + k0 + sw * 8, (char*)Bs + seg * 1024);
    }
    __syncthreads();
#pragma unroll
    for (int ks = 0; ks < 2; ++ks) {
      short8 a[4], bq[4];
#pragma unroll
      for (int mt = 0; mt < 4; ++mt) {
        const int row = wm * 64 + mt * 16 + r16;
        const int c = ks * 4 + g;
        a[mt] = *(const short8*)(As + row * 64 + ((c ^ (row & 7)) * 8));
      }
#pragma unroll
      for (int nt = 0; nt < 4; ++nt) {
        const int row = wn * 64 + nt * 16 + r16;
        const int c = ks * 4 + g;
        bq[nt] = *(const short8*)(Bs + row * 64 + ((c ^ (row & 7)) * 8));
      }
#pragma unroll
      for (int mt = 0; mt < 4; ++mt)
#pragma unroll
        for (int nt = 0; nt < 4; ++nt)
          acc[mt][nt] = __builtin_amdgcn_mfma_f32_16x16x32_bf16(a[mt], bq[nt], acc[mt][nt], 0, 0, 0);
    }
  }
#pragma unroll
  for (int mt = 0; mt < 4; ++mt)
#pragma unroll
    for (int nt = 0; nt < 4; ++nt)
#pragma unroll
      for (int r = 0; r < 4; ++r) {
        const int i = mh * 128 + wm * 64 + mt * 16 + g * 4 + r;
        const int f = ft * 128 + wn * 64 + nt * 16 + r16;
        out[(size_t)b * 2097152 + (size_t)i * 8192 + (size_t)h * 1024 + f] = acc[mt][nt][r];
      }
}

// ---------------- fallback: out = attn(f32) @ x_nT ---------------------------
__global__ __launch_bounds__(256) void ogemm(const float* __restrict__ attn,
                                             const u16* __restrict__ xnt,
                                             float* __restrict__ out) {
  const int orig = blockIdx.x;
  const int wid = (orig & 7) * 256 + (orig >> 3);
  const int ft = wid & 7;
  const int mtile = wid >> 3;
  const int bh = mtile >> 1, mh = mtile & 1;
  const int b = bh >> 3, h = bh & 7;
  __shared__ u16 As[128 * 32];
  __shared__ u16 Bs[128 * 32];
  const int t = threadIdx.x;
  const int lane = t & 63, w = t >> 6;
  const int wm = w >> 1, wn = w & 1;
  const int g = lane >> 4, r16 = lane & 15;
  const float* Ab = attn + ((size_t)bh * 256 + mh * 128) * 4096;
  const u16* Bb = xnt + ((size_t)b * 1024 + ft * 128) * 4096;
  const int arow = t >> 1, ahalf = t & 1;
  const float* ap = Ab + (size_t)arow * 4096 + ahalf * 16;
  const int asw = (arow >> 1) & 3;
  u16* aw0 = As + arow * 32 + (((ahalf * 2 + 0) ^ asw) * 8);
  u16* aw1 = As + arow * 32 + (((ahalf * 2 + 1) ^ asw) * 8);
  f32x4 acc[4][4] = {};
  float4 v0 = *(const float4*)(ap + 0);
  float4 v1 = *(const float4*)(ap + 4);
  float4 v2 = *(const float4*)(ap + 8);
  float4 v3 = *(const float4*)(ap + 12);
  for (int kt = 0; kt < 128; ++kt) {
    __syncthreads();
    short8 pa, pb;
    pa[0] = (short)f2b(v0.x); pa[1] = (short)f2b(v0.y);
    pa[2] = (short)f2b(v0.z); pa[3] = (short)f2b(v0.w);
    pa[4] = (short)f2b(v1.x); pa[5] = (short)f2b(v1.y);
    pa[6] = (short)f2b(v1.z); pa[7] = (short)f2b(v1.w);
    pb[0] = (short)f2b(v2.x); pb[1] = (short)f2b(v2.y);
    pb[2] = (short)f2b(v2.z); pb[3] = (short)f2b(v2.w);
    pb[4] = (short)f2b(v3.x); pb[5] = (short)f2b(v3.y);
    pb[6] = (short)f2b(v3.z); pb[7] = (short)f2b(v3.w);
    *(short8*)aw0 = pa;
    *(short8*)aw1 = pb;
#pragma unroll
    for (int i = 0; i < 2; ++i) {
      const int seg = i * 4 + w;
      const int off = seg * 1024 + lane * 16;
      const int row = off >> 6;
      const int c = (off >> 4) & 3;
      const int sw = c ^ ((row >> 1) & 3);
      gload16(Bb + (size_t)row * 4096 + kt * 32 + sw * 8, (char*)Bs + seg * 1024);
    }
    if (kt < 127) {
      const float* p = ap + (kt + 1) * 32;
      v0 = *(const float4*)(p + 0);
      v1 = *(const float4*)(p + 4);
      v2 = *(const float4*)(p + 8);
      v3 = *(const float4*)(p + 12);
    }
    __syncthreads();
    short8 a[4], bq[4];
#pragma unroll
    for (int mt = 0; mt < 4; ++mt) {
      const int row = wm * 64 + mt * 16 + r16;
      const int sw = g ^ ((row >> 1) & 3);
      a[mt] = *(const short8*)(As + row * 32 + sw * 8);
    }
#pragma unroll
    for (int nt = 0; nt < 4; ++nt) {
      const int row = wn * 64 + nt * 16 + r16;
      const int sw = g ^ ((row >> 1) & 3);
      bq[nt] = *(const short8*)(Bs + row * 32 + sw * 8);
    }
#pragma unroll
    for (int mt = 0; mt < 4; ++mt)
#pragma unroll
      for (int nt = 0; nt < 4; ++nt)
        acc[mt][nt] = __builtin_amdgcn_mfma_f32_16x16x32_bf16(a[mt], bq[nt], acc[mt][nt], 0, 0, 0);
  }
#pragma unroll
  for (int mt = 0; mt < 4; ++mt)
#pragma unroll
    for (int nt = 0; nt < 4; ++nt)
#pragma unroll
      for (int r = 0; r < 4; ++r) {
        const int i = mh * 128 + wm * 64 + mt * 16 + g * 4 + r;
        const int f = ft * 128 + wn * 64 + nt * 16 + r16;
        out[(size_t)b * 2097152 + (size_t)i * 8192 + (size_t)h * 1024 + f] = acc[mt][nt][r];
      }
}

extern "C" void kernel_launch(void* const* d_in, const int* in_sizes, int n_in,
                              void* d_out, int out_size, void* d_ws, size_t ws_size,
                              hipStream_t stream) {
  const float* img_q = (const float*)d_in[0];
  const float* x = (const float*)d_in[1];
  const float* gamma_q = (const float*)d_in[2];
  const float* gamma_x = (const float*)d_in[3];
  const float* wkv = (const float*)d_in[4];

  float* out_f = (float*)d_out;
  float* attn_f = out_f + OUT_ELEMS;

  // Stashes aliasing not-yet-written d_out regions (all dead before overwrite):
  u16* xn = (u16*)attn_f;        // x_n bf16 [65536][1024], 128MB of attn region
  u16* qsb = (u16*)out_f;        // q bf16 (scaled) [16][256][1024], 8MB
  u16* wtb = qsb + 4194304;      // Wt bf16 [128][1024]
  u16* ksb = wtb + 131072;       // k bf16 [16][4096][128], 16MB
  u16* xnt = (u16*)d_ws;         // x_nT bf16 [16][1024][4096], 128MiB

  if (ws_size < (size_t)134217728) return;  // need at least x_nT scratch

  // Fast path: bf16 copy of attn lives in ws after x_nT (256MiB more).
  const bool fast = ws_size >= (size_t)402653184;
  u16* attnb = fast ? (xnt + 67108864) : (u16*)nullptr;

  ln_rows<<<65536, 256, 0, stream>>>(x, gamma_x, xn, 1.0f);
  ln_rows<<<4096, 256, 0, stream>>>(img_q, gamma_q, qsb, SCALE);
  cvt_w<<<128, 256, 0, stream>>>(wkv, wtb);
  transpose_xn<<<dim3(64, 16, 16), 256, 0, stream>>>(xn, xnt);
  kgemm<<<512, 256, 0, stream>>>(xn, wtb, ksb);
  attn_kernel<<<2048, 1024, 0, stream>>>(qsb, ksb, attn_f, attnb);
  if (fast)
    ogemm_bf16<<<2048, 256, 0, stream>>>(attnb, xnt, out_f);
  else
    ogemm<<<2048, 256, 0, stream>>>(attn_f, xnt, out_f);
}

// Round 4
// 917.993 us; speedup vs baseline: 1.2603x; 1.1133x over previous
//
#include <hip/hip_runtime.h>

typedef unsigned short u16;
typedef unsigned int u32;
typedef __attribute__((ext_vector_type(8))) short short8;
typedef __attribute__((ext_vector_type(4))) float f32x4;

// Problem constants: B=16, N=256, T=4096, D=1024, H=8, DH=128
#define SCALE 0.08838834764831845f
#define OUT_ELEMS 33554432ull  // 16*256*8*1024

__device__ __forceinline__ u16 f2b(float f) {  // f32 -> bf16 RNE
  u32 u = __float_as_uint(f);
  u32 r = u + 0x7fffu + ((u >> 16) & 1u);
  return (u16)(r >> 16);
}

__device__ __forceinline__ void gload16(const void* g, void* l) {
  // async global->LDS, 16B per lane; LDS dest = wave-uniform base (+ lane*16 by HW)
  __builtin_amdgcn_global_load_lds((const __attribute__((address_space(1))) void*)g,
                                   (__attribute__((address_space(3))) void*)l, 16, 0, 0);
}

// ---------------- LayerNorm rows of length 1024 -> bf16 (scale folded) -------
__global__ __launch_bounds__(256) void ln_rows(const float* __restrict__ in,
                                               const float* __restrict__ gamma,
                                               u16* __restrict__ out, float scale) {
  const int row = blockIdx.x;
  const int t = threadIdx.x;
  const float4 v = *(const float4*)(in + (size_t)row * 1024 + t * 4);
  float s = v.x + v.y + v.z + v.w;
  float q = v.x * v.x + v.y * v.y + v.z * v.z + v.w * v.w;
#pragma unroll
  for (int m = 32; m; m >>= 1) {
    s += __shfl_down(s, m);
    q += __shfl_down(q, m);
  }
  __shared__ float red[8];
  const int w = t >> 6;
  if ((t & 63) == 0) { red[w] = s; red[4 + w] = q; }
  __syncthreads();
  s = red[0] + red[1] + red[2] + red[3];
  q = red[4] + red[5] + red[6] + red[7];
  const float mu = s * (1.0f / 1024.0f);
  const float var = q * (1.0f / 1024.0f) - mu * mu;
  const float rs = rsqrtf(var + 1e-5f) * scale;
  const float4 g = *(const float4*)(gamma + t * 4);
  ushort4 o;
  o.x = f2b((v.x - mu) * rs * g.x);
  o.y = f2b((v.y - mu) * rs * g.y);
  o.z = f2b((v.z - mu) * rs * g.z);
  o.w = f2b((v.w - mu) * rs * g.w);
  *(ushort4*)(out + (size_t)row * 1024 + t * 4) = o;
}

// ---------------- W_kv[:, :128] -> Wt bf16 [128][1024] -----------------------
__global__ __launch_bounds__(256) void cvt_w(const float* __restrict__ w, u16* __restrict__ wt) {
  const int n = blockIdx.x;  // 0..127
  const int t = threadIdx.x;
  const int d = t * 4;
  ushort4 o;
  o.x = f2b(w[(size_t)(d + 0) * 256 + n]);
  o.y = f2b(w[(size_t)(d + 1) * 256 + n]);
  o.z = f2b(w[(size_t)(d + 2) * 256 + n]);
  o.w = f2b(w[(size_t)(d + 3) * 256 + n]);
  *(ushort4*)(wt + (size_t)n * 1024 + d) = o;
}

// ---------------- x_n [b][4096][1024] -> x_nT [b][1024][4096] (bf16) ---------
__global__ __launch_bounds__(256) void transpose_xn(const u16* __restrict__ xn,
                                                    u16* __restrict__ xnt) {
  const int jt = blockIdx.x, dt = blockIdx.y, b = blockIdx.z;
  __shared__ u16 tile[64][72];  // pad 8 keeps 16B alignment per row
  const int t = threadIdx.x;
  const size_t src = ((size_t)b * 4096 + jt * 64) * 1024 + dt * 64;
#pragma unroll
  for (int p = 0; p < 2; ++p) {
    const int idx = t + 256 * p;
    const int j = idx >> 3, c = idx & 7;
    *(short8*)(&tile[j][c * 8]) = *(const short8*)(xn + src + (size_t)j * 1024 + c * 8);
  }
  __syncthreads();
  const size_t dst = ((size_t)b * 1024 + dt * 64) * 4096 + jt * 64;
#pragma unroll
  for (int p = 0; p < 2; ++p) {
    const int idx = t + 256 * p;
    const int d = idx >> 3, jj = idx & 7;
    short8 o;
#pragma unroll
    for (int e = 0; e < 8; ++e) o[e] = (short)tile[jj * 8 + e][d];
    *(short8*)(xnt + dst + (size_t)d * 4096 + jj * 8) = o;
  }
}

// ---------------- k = x_n @ W[:, :128]  (M=65536, N=128, K=1024) -------------
__global__ __launch_bounds__(256) void kgemm(const u16* __restrict__ xn,
                                             const u16* __restrict__ wt,
                                             u16* __restrict__ ks) {
  __shared__ u16 As[128 * 32];
  __shared__ u16 Bs[128 * 32];
  const int t = threadIdx.x;
  const int lane = t & 63, w = t >> 6;
  const int wm = w >> 1, wn = w & 1;
  const int j0 = blockIdx.x * 128;
  const int g = lane >> 4, r16 = lane & 15;
  f32x4 acc[4][4] = {};
  for (int k0 = 0; k0 < 1024; k0 += 32) {
    __syncthreads();
#pragma unroll
    for (int i = 0; i < 2; ++i) {
      const int seg = i * 4 + w;
      const int off = seg * 1024 + lane * 16;  // linear LDS byte offset
      const int row = off >> 6;                // 64B per row (32 bf16)
      const int c = (off >> 4) & 3;            // 16B chunk in row
      const int sw = c ^ ((row >> 1) & 3);     // inverse-swizzled global source
      gload16(xn + ((size_t)(j0 + row)) * 1024 + k0 + sw * 8, (char*)As + seg * 1024);
      gload16(wt + ((size_t)row) * 1024 + k0 + sw * 8, (char*)Bs + seg * 1024);
    }
    __syncthreads();
    short8 a[4], bq[4];
#pragma unroll
    for (int mt = 0; mt < 4; ++mt) {
      const int row = wm * 64 + mt * 16 + r16;
      const int sw = g ^ ((row >> 1) & 3);
      a[mt] = *(const short8*)(As + row * 32 + sw * 8);
    }
#pragma unroll
    for (int nt = 0; nt < 4; ++nt) {
      const int row = wn * 64 + nt * 16 + r16;
      const int sw = g ^ ((row >> 1) & 3);
      bq[nt] = *(const short8*)(Bs + row * 32 + sw * 8);
    }
#pragma unroll
    for (int mt = 0; mt < 4; ++mt)
#pragma unroll
      for (int nt = 0; nt < 4; ++nt)
        acc[mt][nt] = __builtin_amdgcn_mfma_f32_16x16x32_bf16(a[mt], bq[nt], acc[mt][nt], 0, 0, 0);
  }
#pragma unroll
  for (int mt = 0; mt < 4; ++mt)
#pragma unroll
    for (int nt = 0; nt < 4; ++nt)
#pragma unroll
      for (int r = 0; r < 4; ++r) {
        const int j = j0 + wm * 64 + mt * 16 + g * 4 + r;
        const int n = wn * 64 + nt * 16 + r16;
        ks[(size_t)j * 128 + n] = f2b(acc[mt][nt][r]);
      }
}

// ---------------- sim + softmax -> attn (f32) [+ bf16 copy] ------------------
// block = (b, h, 16 q-rows); 16 waves, wave w covers j in [w*256, w*256+256).
// SWAPPED QK^T: acc = mfma(K_frag, Q_frag) -> lane holds col i = r16 (q-row),
// rows j = g*4 + r (consecutive!). Enables full-line dwordx4 attn stores and
// shfl-only row reduction.
__global__ __launch_bounds__(1024) void attn_kernel(const u16* __restrict__ qs,
                                                    const u16* __restrict__ ks,
                                                    float* __restrict__ attn,
                                                    u16* __restrict__ attnb) {
  const int blk = blockIdx.x;
  const int it = blk & 15, h = (blk >> 4) & 7, b = blk >> 7;
  const int i0 = it * 16;
  const int t = threadIdx.x;
  const int lane = t & 63, w = t >> 6;
  const int g = lane >> 4, r16 = lane & 15;
  __shared__ u16 Q[16 * 128];
  __shared__ u16 rep[16 * 1024];  // per-wave 1024 u16 slice (16 rows x 64 j), reused x4
  __shared__ float redm[256];
  __shared__ float reds[256];
  if (t < 256) {
    const int row = t >> 4, c = t & 15;
    const int sw = c ^ (row & 7);
    *(short8*)(Q + row * 128 + sw * 8) =
        *(const short8*)(qs + ((size_t)(b * 256 + i0 + row)) * 1024 + h * 128 + c * 8);
  }
  __syncthreads();
  short8 a[4];
#pragma unroll
  for (int kp = 0; kp < 4; ++kp) {
    const int c = kp * 4 + g;
    const int sw = c ^ (r16 & 7);
    a[kp] = *(const short8*)(Q + r16 * 128 + sw * 8);
  }
  const u16* kb = ks + (size_t)b * 4096 * 128;
  const int j0 = w * 256;
  f32x4 acc[16] = {};
#pragma unroll
  for (int kp = 0; kp < 4; ++kp) {
#pragma unroll
    for (int nt = 0; nt < 16; ++nt) {
      const short8 bv = *(const short8*)(kb + (size_t)(j0 + nt * 16 + r16) * 128 + kp * 32 + g * 8);
      // swapped: K rows are the M dim (j), Q rows are the N dim (i)
      acc[nt] = __builtin_amdgcn_mfma_f32_16x16x32_bf16(bv, a[kp], acc[nt], 0, 0, 0);
    }
  }
  // lane holds 64 values: j = j0 + nt*16 + g*4 + r, all for q-row i = r16
  float mx = acc[0][0];
#pragma unroll
  for (int nt = 0; nt < 16; ++nt)
#pragma unroll
    for (int r = 0; r < 4; ++r) mx = fmaxf(mx, acc[nt][r]);
  mx = fmaxf(mx, __shfl_xor(mx, 16));
  mx = fmaxf(mx, __shfl_xor(mx, 32));  // now max over this wave's 256 j, per row r16
  if (lane < 16) redm[w * 16 + lane] = mx;
  __syncthreads();
  float m = redm[r16];
#pragma unroll
  for (int w2 = 1; w2 < 16; ++w2) m = fmaxf(m, redm[w2 * 16 + r16]);
  float sm = 0.f;
#pragma unroll
  for (int nt = 0; nt < 16; ++nt)
#pragma unroll
    for (int r = 0; r < 4; ++r) {
      const float p = __expf(acc[nt][r] - m);
      acc[nt][r] = p;
      sm += p;
    }
  sm += __shfl_xor(sm, 16);
  sm += __shfl_xor(sm, 32);
  if (lane < 16) reds[w * 16 + lane] = sm;
  __syncthreads();
  float s = reds[r16];
#pragma unroll
  for (int w2 = 1; w2 < 16; ++w2) s += reds[w2 * 16 + r16];
  const float inv = 1.0f / s;
#pragma unroll
  for (int nt = 0; nt < 16; ++nt) acc[nt] *= inv;

  // f32 attn: 16 dwordx4 stores, each instr = 16 rows x 64B full aligned lines
  float* arow = attn + ((size_t)((b * 8 + h) * 256 + i0 + r16)) * 4096 + j0;
#pragma unroll
  for (int nt = 0; nt < 16; ++nt)
    *(f32x4*)(arow + nt * 16 + g * 4) = acc[nt];

  // bf16 attnb via per-wave LDS repack -> contiguous full-line stores
  if (attnb) {
    u16* rslice = rep + w * 1024;
    u16* brow = attnb + ((size_t)((b * 8 + h) * 256 + i0)) * 4096 + j0;
    const int r7s = (r16 & 7) << 1;
    for (int q4 = 0; q4 < 4; ++q4) {
#pragma unroll
      for (int ntq = 0; ntq < 4; ++ntq) {
        const f32x4 v = acc[q4 * 4 + ntq];
        const u32 lo = (u32)f2b(v[0]) | ((u32)f2b(v[1]) << 16);
        const u32 hi = (u32)f2b(v[2]) | ((u32)f2b(v[3]) << 16);
        const int c8 = (ntq * 4 + g) ^ r7s;  // 8B-chunk XOR swizzle (keeps 16B pairing)
        *(uint2*)(rslice + r16 * 64 + c8 * 4) = make_uint2(lo, hi);
      }
      asm volatile("s_waitcnt lgkmcnt(0)" ::: "memory");
      __builtin_amdgcn_sched_barrier(0);
#pragma unroll
      for (int ih = 0; ih < 2; ++ih) {
        const int row = ih * 8 + (lane >> 3);
        const int c16 = lane & 7;
        const int c8 = (c16 * 2) ^ ((row & 7) << 1);
        const uint4 d = *(const uint4*)(rslice + row * 64 + c8 * 4);
        *(uint4*)(brow + (size_t)row * 4096 + q4 * 64 + c16 * 8) = d;
      }
      asm volatile("s_waitcnt lgkmcnt(0)" ::: "memory");
      __builtin_amdgcn_sched_barrier(0);
    }
  }
}

// ---------------- out = attnb @ x_nT  256x256 tile, counted-vmcnt pipeline ---
// Per (b,h): C[256 x 1024] = attnb[256 x 4096] @ xnt[f][j]^T. Grid: 16b*8h*4ft.
// 8 waves (2M x 4N), wave tile 128x64, acc[8][4]. BK=32, dbuf 64KB LDS.
// Schedule/iter: {ds_read 12 b128; lgkmcnt(0); barrier; STAGE(t+2) 4 gloads;
//   setprio(1); 32 MFMA; setprio(0); vmcnt(4) counted (never 0 mid-loop); barrier}
__global__ __launch_bounds__(512, 2) void ogemm256(const u16* __restrict__ attnb,
                                                   const u16* __restrict__ xnt,
                                                   float* __restrict__ out) {
  __shared__ char S[65536];  // A: [buf*16KB], B: 32768 + [buf*16KB]; rows of 64B
  const int orig = blockIdx.x;
  const int wid = (orig & 7) * 64 + (orig >> 3);  // XCD-chunked, bijective (512%8==0)
  const int b = wid >> 5, ft = (wid >> 3) & 3, h = wid & 7;  // 8 h-blocks share B panel
  const int t = threadIdx.x;
  const int lane = t & 63, w = t >> 6;
  const int wm = w >> 2, wn = w & 3;  // 2 x 4 waves
  const int g = lane >> 4, r16 = lane & 15;
  const u16* Ab = attnb + ((size_t)(b * 8 + h) * 256) * 4096;
  const u16* Bb = xnt + ((size_t)b * 1024 + ft * 256) * 4096;

  // staging source coords for the 4 per-thread loads (2 A segs + 2 B segs)
  // lin = sg*8192 + t*16 ; row = lin>>6 (64B rows) ; chunk c=(lin>>4)&3 ; src c^(row&3)
  const int lin0 = t * 16;
  const int row0 = lin0 >> 6, sc0 = ((lin0 >> 4) & 3) ^ (row0 & 3);
  const int lin1 = 8192 + t * 16;
  const int row1 = lin1 >> 6, sc1 = ((lin1 >> 4) & 3) ^ (row1 & 3);
  const int wuni = (t >> 6) * 1024;  // wave-uniform LDS offset within seg

#define STAGE(buf, k0)                                                              \
  do {                                                                              \
    gload16(Ab + (size_t)row0 * 4096 + (k0) + sc0 * 8, S + (buf)*16384 + wuni);     \
    gload16(Ab + (size_t)row1 * 4096 + (k0) + sc1 * 8, S + (buf)*16384 + 8192 + wuni); \
    gload16(Bb + (size_t)row0 * 4096 + (k0) + sc0 * 8, S + 32768 + (buf)*16384 + wuni); \
    gload16(Bb + (size_t)row1 * 4096 + (k0) + sc1 * 8, S + 32768 + (buf)*16384 + 8192 + wuni); \
  } while (0)

  f32x4 acc[8][4] = {};
  STAGE(0, 0);
  STAGE(1, 32);
  asm volatile("s_waitcnt vmcnt(4)" ::: "memory");  // tile 0 done; tile 1 in flight
  __builtin_amdgcn_s_barrier();

  const int r3 = r16 & 3;
  for (int t64 = 0; t64 < 128; ++t64) {
    const int buf = t64 & 1;
    const char* A0 = S + buf * 16384;
    const char* B0 = S + 32768 + buf * 16384;
    short8 af[8], bf[4];
    {
      const int ch = (g ^ r3) * 16;
#pragma unroll
      for (int mt = 0; mt < 8; ++mt)
        af[mt] = *(const short8*)(A0 + (wm * 128 + mt * 16 + r16) * 64 + ch);
#pragma unroll
      for (int nt = 0; nt < 4; ++nt)
        bf[nt] = *(const short8*)(B0 + (wn * 64 + nt * 16 + r16) * 64 + ch);
    }
    asm volatile("s_waitcnt lgkmcnt(0)" ::: "memory");
    __builtin_amdgcn_sched_barrier(0);
    __builtin_amdgcn_s_barrier();  // all waves done reading buf -> free to restage
    if (t64 + 2 < 128) STAGE(buf, (t64 + 2) * 32);
    __builtin_amdgcn_s_setprio(1);
#pragma unroll
    for (int mt = 0; mt < 8; ++mt)
#pragma unroll
      for (int nt = 0; nt < 4; ++nt)
        acc[mt][nt] = __builtin_amdgcn_mfma_f32_16x16x32_bf16(af[mt], bf[nt], acc[mt][nt], 0, 0, 0);
    __builtin_amdgcn_s_setprio(0);
    if (t64 + 2 < 128)
      asm volatile("s_waitcnt vmcnt(4)" ::: "memory");  // t+1 staged; t+2 stays in flight
    else
      asm volatile("s_waitcnt vmcnt(0)" ::: "memory");  // epilogue drain
    __builtin_amdgcn_s_barrier();
  }
#undef STAGE

  float* ob = out + (size_t)b * 2097152 + (size_t)h * 1024;
#pragma unroll
  for (int mt = 0; mt < 8; ++mt)
#pragma unroll
    for (int nt = 0; nt < 4; ++nt)
#pragma unroll
      for (int r = 0; r < 4; ++r) {
        const int i = wm * 128 + mt * 16 + g * 4 + r;
        const int f = ft * 256 + wn * 64 + nt * 16 + r16;
        ob[(size_t)i * 8192 + f] = acc[mt][nt][r];
      }
}

// ---------------- fallback: out = attn(f32) @ x_nT ---------------------------
__global__ __launch_bounds__(256) void ogemm(const float* __restrict__ attn,
                                             const u16* __restrict__ xnt,
                                             float* __restrict__ out) {
  const int orig = blockIdx.x;
  const int wid = (orig & 7) * 256 + (orig >> 3);
  const int ft = wid & 7;
  const int mtile = wid >> 3;
  const int bh = mtile >> 1, mh = mtile & 1;
  const int b = bh >> 3, h = bh & 7;
  __shared__ u16 As[128 * 32];
  __shared__ u16 Bs[128 * 32];
  const int t = threadIdx.x;
  const int lane = t & 63, w = t >> 6;
  const int wm = w >> 1, wn = w & 1;
  const int g = lane >> 4, r16 = lane & 15;
  const float* Ab = attn + ((size_t)bh * 256 + mh * 128) * 4096;
  const u16* Bb = xnt + ((size_t)b * 1024 + ft * 128) * 4096;
  const int arow = t >> 1, ahalf = t & 1;
  const float* ap = Ab + (size_t)arow * 4096 + ahalf * 16;
  const int asw = (arow >> 1) & 3;
  u16* aw0 = As + arow * 32 + (((ahalf * 2 + 0) ^ asw) * 8);
  u16* aw1 = As + arow * 32 + (((ahalf * 2 + 1) ^ asw) * 8);
  f32x4 acc[4][4] = {};
  float4 v0 = *(const float4*)(ap + 0);
  float4 v1 = *(const float4*)(ap + 4);
  float4 v2 = *(const float4*)(ap + 8);
  float4 v3 = *(const float4*)(ap + 12);
  for (int kt = 0; kt < 128; ++kt) {
    __syncthreads();
    short8 pa, pb;
    pa[0] = (short)f2b(v0.x); pa[1] = (short)f2b(v0.y);
    pa[2] = (short)f2b(v0.z); pa[3] = (short)f2b(v0.w);
    pa[4] = (short)f2b(v1.x); pa[5] = (short)f2b(v1.y);
    pa[6] = (short)f2b(v1.z); pa[7] = (short)f2b(v1.w);
    pb[0] = (short)f2b(v2.x); pb[1] = (short)f2b(v2.y);
    pb[2] = (short)f2b(v2.z); pb[3] = (short)f2b(v2.w);
    pb[4] = (short)f2b(v3.x); pb[5] = (short)f2b(v3.y);
    pb[6] = (short)f2b(v3.z); pb[7] = (short)f2b(v3.w);
    *(short8*)aw0 = pa;
    *(short8*)aw1 = pb;
#pragma unroll
    for (int i = 0; i < 2; ++i) {
      const int seg = i * 4 + w;
      const int off = seg * 1024 + lane * 16;
      const int row = off >> 6;
      const int c = (off >> 4) & 3;
      const int sw = c ^ ((row >> 1) & 3);
      gload16(Bb + (size_t)row * 4096 + kt * 32 + sw * 8, (char*)Bs + seg * 1024);
    }
    if (kt < 127) {
      const float* p = ap + (kt + 1) * 32;
      v0 = *(const float4*)(p + 0);
      v1 = *(const float4*)(p + 4);
      v2 = *(const float4*)(p + 8);
      v3 = *(const float4*)(p + 12);
    }
    __syncthreads();
    short8 a[4], bq[4];
#pragma unroll
    for (int mt = 0; mt < 4; ++mt) {
      const int row = wm * 64 + mt * 16 + r16;
      const int sw = g ^ ((row >> 1) & 3);
      a[mt] = *(const short8*)(As + row * 32 + sw * 8);
    }
#pragma unroll
    for (int nt = 0; nt < 4; ++nt) {
      const int row = wn * 64 + nt * 16 + r16;
      const int sw = g ^ ((row >> 1) & 3);
      bq[nt] = *(const short8*)(Bs + row * 32 + sw * 8);
    }
#pragma unroll
    for (int mt = 0; mt < 4; ++mt)
#pragma unroll
      for (int nt = 0; nt < 4; ++nt)
        acc[mt][nt] = __builtin_amdgcn_mfma_f32_16x16x32_bf16(a[mt], bq[nt], acc[mt][nt], 0, 0, 0);
  }
#pragma unroll
  for (int mt = 0; mt < 4; ++mt)
#pragma unroll
    for (int nt = 0; nt < 4; ++nt)
#pragma unroll
      for (int r = 0; r < 4; ++r) {
        const int i = mh * 128 + wm * 64 + mt * 16 + g * 4 + r;
        const int f = ft * 128 + wn * 64 + nt * 16 + r16;
        out[(size_t)b * 2097152 + (size_t)i * 8192 + (size_t)h * 1024 + f] = acc[mt][nt][r];
      }
}

extern "C" void kernel_launch(void* const* d_in, const int* in_sizes, int n_in,
                              void* d_out, int out_size, void* d_ws, size_t ws_size,
                              hipStream_t stream) {
  const float* img_q = (const float*)d_in[0];
  const float* x = (const float*)d_in[1];
  const float* gamma_q = (const float*)d_in[2];
  const float* gamma_x = (const float*)d_in[3];
  const float* wkv = (const float*)d_in[4];

  float* out_f = (float*)d_out;
  float* attn_f = out_f + OUT_ELEMS;

  // Stashes aliasing not-yet-written d_out regions (all dead before overwrite):
  u16* xn = (u16*)attn_f;        // x_n bf16 [65536][1024], 128MB of attn region
  u16* qsb = (u16*)out_f;        // q bf16 (scaled) [16][256][1024], 8MB
  u16* wtb = qsb + 4194304;      // Wt bf16 [128][1024]
  u16* ksb = wtb + 131072;       // k bf16 [16][4096][128], 16MB
  u16* xnt = (u16*)d_ws;         // x_nT bf16 [16][1024][4096], 128MiB

  if (ws_size < (size_t)134217728) return;  // need at least x_nT scratch

  // Fast path: bf16 copy of attn lives in ws after x_nT (256MiB more).
  const bool fast = ws_size >= (size_t)402653184;
  u16* attnb = fast ? (xnt + 67108864) : (u16*)nullptr;

  ln_rows<<<65536, 256, 0, stream>>>(x, gamma_x, xn, 1.0f);
  ln_rows<<<4096, 256, 0, stream>>>(img_q, gamma_q, qsb, SCALE);
  cvt_w<<<128, 256, 0, stream>>>(wkv, wtb);
  transpose_xn<<<dim3(64, 16, 16), 256, 0, stream>>>(xn, xnt);
  kgemm<<<512, 256, 0, stream>>>(xn, wtb, ksb);
  attn_kernel<<<2048, 1024, 0, stream>>>(qsb, ksb, attn_f, attnb);
  if (fast)
    ogemm256<<<512, 512, 0, stream>>>(attnb, xnt, out_f);
  else
    ogemm<<<2048, 256, 0, stream>>>(attn_f, xnt, out_f);
}